// Round 10
// baseline (585.594 us; speedup 1.0000x reference)
//
#include <hip/hip_runtime.h>

// Capsule routing B=32 I=64 J=1152 K=32 M=16, routings=3, via MFMA.
// u_hat[k,b] per (i,j) = one v_mfma_f32_32x32x16_bf16.
// Sweep 1 (k_s<1>) streams f32 W (3-MFMA split accuracy) AND emits bf16 W.
// Sweeps 2-5 read bf16 W (2 MFMA; x hi/lo split). IT=4 everywhere (proven).
// Round-10: k_redsq FUSED into k_s tail (last-block-per-iy via device-scope
// atomic counter + threadfence): the 72nd-arriving jb-block reduces the 72
// spart partials for its 4 i's, applies squash, writes ot (or out on the
// final sweep) and zeroes the NEXT iteration's z. z double-buffered (z0/z1)
// so a k_s never clears the buffer it reads. Dispatches 8 -> 6.
// Softmax without max-subtraction (|b|<~25, f32-safe): z accumulated by
// atomicAdd in k_ag; k_s uses c = exp(b)/z. spart stored bf16.
// ws: spart ushort[4718592] | br f32[2359296] | z0 f32[36864] |
//     z1 f32[36864] | ot f32[65536] | cnt int[48] | Wbf ushort[37748736]

#define Ii 64
#define Jj 1152
#define Kk 32
#define Bb 32
#define NJB2 72     // J / 16

typedef short  bf16x8 __attribute__((ext_vector_type(8)));
typedef float  f32x16 __attribute__((ext_vector_type(16)));
typedef float  f32x4  __attribute__((ext_vector_type(4)));

__device__ __forceinline__ void split2(float a, float b, unsigned &hi, unsigned &lo){
  unsigned ua = __float_as_uint(a), ub = __float_as_uint(b);
  unsigned ha = ua & 0xFFFF0000u, hb = ub & 0xFFFF0000u;
  hi = (ha >> 16) | hb;
  float la = a - __uint_as_float(ha);
  float lb = b - __uint_as_float(hb);
  lo = ((__float_as_uint(la) & 0xFFFF0000u) >> 16) | (__float_as_uint(lb) & 0xFFFF0000u);
}

__device__ __forceinline__ void split8(const float* v, bf16x8 &hi, bf16x8 &lo){
  union U { bf16x8 v; unsigned u[4]; } H, L;
#pragma unroll
  for (int p=0;p<4;p++) split2(v[2*p], v[2*p+1], H.u[p], L.u[p]);
  hi = H.v; lo = L.v;
}

__device__ __forceinline__ ushort f2bf_rne(float f){
  unsigned u = __float_as_uint(f);
  return (ushort)((u + 0x7FFFu + ((u >> 16) & 1u)) >> 16);
}

__device__ __forceinline__ float bf_lo(unsigned u){ return __uint_as_float(u << 16); }
__device__ __forceinline__ float bf_hi(unsigned u){ return __uint_as_float(u & 0xFFFF0000u); }

#define MFMA(A,B,C) __builtin_amdgcn_mfma_f32_32x32x16_bf16(A,B,C,0,0,0)

// ---- s pass (IT=4) with FUSED reduce+squash tail -------------------------
// FIRST=1: read f32 W, emit bf16 W, 3-MFMA split. FIRST=0: bf16 W, 2-MFMA.
// FINAL=0: tail writes ot[i][k][b] and zeroes zclr. FINAL=1: writes out[b][i][k].
template<int FIRST, int FINAL>
__global__ __launch_bounds__(256, 2)
void k_s(const float* __restrict__ Wp, const ushort* __restrict__ Wbi,
         ushort* __restrict__ Wbo, const float* __restrict__ xp,
         const float* __restrict__ brt, const float* __restrict__ zp,
         ushort* __restrict__ spart, int* __restrict__ cnt,
         float* __restrict__ zclr, float* __restrict__ outp)
{
  __shared__ float red[4*1088];
  __shared__ int lastFlag;
  const int t  = threadIdx.x;
  const int w  = t >> 6, lane = t & 63;
  const int kk = lane & 31;
  const int h  = lane >> 5;
  const int b  = lane & 31;
  const int i0 = blockIdx.y * 4;
  const int j0 = blockIdx.x * 16 + w * 4;   // this wave's 4 j's

  // x fragments: load + split once, reuse across all 4 i
  bf16x8 Bh[4], Bl[4];
  float zi[4];
#pragma unroll
  for (int jj=0;jj<4;jj++){
    const int j = j0 + jj;
    float x8[8];
    *(f32x4*)(x8)   = *(const f32x4*)(xp + (b*Jj + j)*16 + h*8);
    *(f32x4*)(x8+4) = *(const f32x4*)(xp + (b*Jj + j)*16 + h*8 + 4);
    split8(x8, Bh[jj], Bl[jj]);
    if (!FIRST) zi[jj] = 1.0f / zp[j*32 + b];
  }

  f32x16 acc[4];
#pragma unroll
  for (int ii=0;ii<4;ii++) acc[ii] = {};

#pragma unroll
  for (int ii=0; ii<4; ++ii){
    const int i = i0 + ii;
#pragma unroll
    for (int jj=0;jj<4;jj++){
      const size_t eoff = (size_t)(i*Jj + j0+jj)*512 + kk*16 + h*8;
      f32x16 d = {};
      if (FIRST){
        float w8[8];
        *(f32x4*)(w8)   = *(const f32x4*)(Wp + eoff);
        *(f32x4*)(w8+4) = *(const f32x4*)(Wp + eoff + 4);
        bf16x8 Ah, Al;
        split8(w8, Ah, Al);
        *reinterpret_cast<bf16x8*>(Wbo + eoff) = Ah;   // emit bf16 W
        d = MFMA(Ah, Bh[jj], d);
        d = MFMA(Ah, Bl[jj], d);
        d = MFMA(Al, Bh[jj], d);
      } else {
        const bf16x8 Ah = *reinterpret_cast<const bf16x8*>(Wbi + eoff);
        d = MFMA(Ah, Bh[jj], d);
        d = MFMA(Ah, Bl[jj], d);
      }
      float cw;
      if (FIRST) cw = 0.015625f;
      else {
        const float bv = brt[(i*Jj + j0+jj)*32 + b];
        cw = __expf(bv) * zi[jj];
      }
#pragma unroll
      for (int r=0;r<16;r++) acc[ii][r] += cw * d[r];
    }
  }

  // epilogue: cross-wave reduce per i (stride-17 rows: conflict-free)
#pragma unroll
  for (int ii=0; ii<4; ++ii){
    __syncthreads();
#pragma unroll
    for (int r=0;r<16;r++) red[w*1088 + lane*17 + r] = acc[ii][r];
    __syncthreads();
    ushort4 outv;
    {
      float s0=0.f, s1=0.f, s2v=0.f, s3=0.f;
#pragma unroll
      for (int q=0;q<4;q++){
        const int v  = t*4 + q;
        const int lv = v >> 4, r = v & 15;
        float sum = 0.f;
#pragma unroll
        for (int ww=0;ww<4;ww++) sum += red[ww*1088 + lv*17 + r];
        if (q==0) s0=sum; else if (q==1) s1=sum; else if (q==2) s2v=sum; else s3=sum;
      }
      outv.x = f2bf_rne(s0); outv.y = f2bf_rne(s1);
      outv.z = f2bf_rne(s2v); outv.w = f2bf_rne(s3);
    }
    *(ushort4*)&spart[((size_t)blockIdx.x*Ii + (i0+ii))*1024 + t*4] = outv;
  }

  // ---- fused reduce+squash tail: last-arriving block of this iy ----------
  __threadfence();                 // release: spart stores visible device-wide
  __syncthreads();
  if (t == 0){
    const int old = atomicAdd(&cnt[blockIdx.y], 1);
    lastFlag = (old == NJB2-1);
  }
  __syncthreads();
  if (!lastFlag) return;
  __threadfence();                 // acquire before reading others' spart

  {
    const int wv = t >> 6, u = t & 63;
    const int i  = i0 + wv;        // one wave per i
    float av[16];
#pragma unroll
    for (int r=0;r<16;r++) av[r] = 0.f;
    for (int jb=0; jb<NJB2; ++jb){
      const ushort* p = &spart[((size_t)jb*Ii + i)*1024 + u*16];
      const uint4 a = *(const uint4*)(p);
      const uint4 c = *(const uint4*)(p+8);
      av[0] += bf_lo(a.x);  av[1] += bf_hi(a.x);
      av[2] += bf_lo(a.y);  av[3] += bf_hi(a.y);
      av[4] += bf_lo(a.z);  av[5] += bf_hi(a.z);
      av[6] += bf_lo(a.w);  av[7] += bf_hi(a.w);
      av[8] += bf_lo(c.x);  av[9] += bf_hi(c.x);
      av[10]+= bf_lo(c.y);  av[11]+= bf_hi(c.y);
      av[12]+= bf_lo(c.z);  av[13]+= bf_hi(c.z);
      av[14]+= bf_lo(c.w);  av[15]+= bf_hi(c.w);
    }
    const int b2 = u & 31, hh = u >> 5;
    float ss = 0.f;
#pragma unroll
    for (int r=0;r<16;r++) ss += av[r]*av[r];
    ss += __shfl_xor(ss, 32);
    const float scale = ss/(1.f+ss) * rsqrtf(ss + 1e-7f);
#pragma unroll
    for (int r=0;r<16;r++){
      const int kcap = (r & 3) + 8*(r >> 2) + 4*hh;
      const float val = av[r]*scale;
      if (FINAL) outp[((size_t)b2*Ii + i)*Kk + kcap] = val;
      else       outp[(i*Kk + kcap)*Bb + b2] = val;
    }
    if (!FINAL){
      const int base = blockIdx.y * 2304;   // 16 iy x 2304 = 36864
      for (int q = t; q < 2304; q += 256) zclr[base + q] = 0.f;
    }
  }
}

// ---- agree pass (bf16 W, IT=4): br_t (+)= o.u_hat; z[j,b] += exp(br_new) -
template<int ADD>
__global__ __launch_bounds__(256, 2)
void k_ag(const ushort* __restrict__ Wb, const float* __restrict__ xp,
          const float* __restrict__ ot, float* __restrict__ brt,
          float* __restrict__ zp)
{
  const int t  = threadIdx.x;
  const int w  = t >> 6, lane = t & 63;
  const int kk = lane & 31;
  const int h  = lane >> 5;
  const int b  = lane & 31;
  const int i0 = blockIdx.y * 4;
  const int j0 = blockIdx.x * 16 + w * 4;

  bf16x8 Bh[4], Bl[4];
#pragma unroll
  for (int jj=0;jj<4;jj++){
    const int j = j0 + jj;
    float x8[8];
    *(f32x4*)(x8)   = *(const f32x4*)(xp + (b*Jj + j)*16 + h*8);
    *(f32x4*)(x8+4) = *(const f32x4*)(xp + (b*Jj + j)*16 + h*8 + 4);
    split8(x8, Bh[jj], Bl[jj]);
  }

  float ez[4] = {0.f, 0.f, 0.f, 0.f};

#pragma unroll
  for (int ii=0; ii<4; ++ii){
    const int i = i0 + ii;
    float ov[16];
#pragma unroll
    for (int r=0;r<16;r++){
      const int kcap = (r & 3) + 8*(r >> 2) + 4*h;
      ov[r] = ot[(i*Kk + kcap)*Bb + b];
    }
#pragma unroll
    for (int jj=0;jj<4;jj++){
      const size_t eoff = (size_t)(i*Jj + j0+jj)*512 + kk*16 + h*8;
      const bf16x8 Ah = *reinterpret_cast<const bf16x8*>(Wb + eoff);
      f32x16 d = {};
      d = MFMA(Ah, Bh[jj], d);
      d = MFMA(Ah, Bl[jj], d);
      float ap = 0.f;
#pragma unroll
      for (int r=0;r<16;r++) ap += ov[r]*d[r];
      ap += __shfl_xor(ap, 32);
      if (h == 0){
        const int idx = (i*Jj + j0+jj)*32 + b;
        const float prev = ADD ? brt[idx] : 0.f;
        const float bn = prev + ap;
        brt[idx] = bn;
        ez[jj] += __expf(bn);
      }
    }
  }
  if (h == 0){
#pragma unroll
    for (int jj=0;jj<4;jj++)
      atomicAdd(&zp[(j0+jj)*32 + b], ez[jj]);
  }
}

extern "C" void kernel_launch(void* const* d_in, const int* in_sizes, int n_in,
                              void* d_out, int out_size, void* d_ws, size_t ws_size,
                              hipStream_t stream)
{
  const float* x  = (const float*)d_in[0];   // [B,J,M]
  const float* Wp = (const float*)d_in[1];   // [I,J,K,M]
  float* out = (float*)d_out;                // [B,I,K]
  float* ws  = (float*)d_ws;
  ushort* spart = (ushort*)ws;               // 4718592 ushorts (9.4MB)
  float* br    = ws + 2359296;               // 2359296 floats
  float* z0    = ws + 4718592;               // 36864 floats
  float* z1    = ws + 4755456;               // 36864 floats
  float* ot    = ws + 4792320;               // 65536 floats
  int*   cnt   = (int*)(ws + 4857856);       // 48 ints (16 per k_s sweep)
  ushort* Wbf  = (ushort*)(ws + 4857920);    // 37748736 ushorts (75.5MB)

  dim3 gs(NJB2, 16), bs(256);

  hipMemsetAsync(cnt, 0, 48*sizeof(int), stream);

  // iter 0 (c uniform 1/64); k_s<1> emits bf16 W; tail -> ot, zeroes z0
  k_s<1,0><<<gs, bs, 0, stream>>>(Wp, nullptr, Wbf, x, nullptr, nullptr,
                                  spart, cnt, z0, ot);
  k_ag<0><<<gs, bs, 0, stream>>>(Wbf, x, ot, br, z0);

  // iter 1: reads z0; tail -> ot, zeroes z1
  k_s<0,0><<<gs, bs, 0, stream>>>(nullptr, Wbf, nullptr, x, br, z0,
                                  spart, cnt+16, z1, ot);
  k_ag<1><<<gs, bs, 0, stream>>>(Wbf, x, ot, br, z1);

  // iter 2: reads z1; tail -> out
  k_s<0,1><<<gs, bs, 0, stream>>>(nullptr, Wbf, nullptr, x, br, z1,
                                  spart, cnt+32, nullptr, out);
}

// Round 11
// 152.890 us; speedup vs baseline: 3.8302x; 3.8302x over previous
//
#include <hip/hip_runtime.h>

// Capsule routing B=32 I=64 J=1152 K=32 M=16, routings=3, via MFMA.
// u_hat[k,b] per (i,j) = one v_mfma_f32_32x32x16_bf16.
// Sweep 1 (k_s<1>) streams f32 W (3-MFMA split accuracy) AND emits bf16 W.
// Sweeps 2-5 read bf16 W (2 MFMA; x hi/lo split). IT=4 everywhere (proven
// round-7 best). spart stored bf16. Softmax without max-subtraction
// (|b|<~25, f32-safe): z accumulated by atomicAdd in k_ag; k_s uses
// c = exp(b)/z; z zeroed inside k_redsq (ZZ) -> no memsets.
// Round-11: bf16 sweeps at __launch_bounds__(256,4) (occupancy 2->4
// blocks/CU, traffic unchanged). Round-10's device-scope-fence fusion
// REVERTED (per-block threadfence on multi-XCD = L2 flush storm, 4x slower).
// ws: spart ushort[4718592] | br f32[2359296] | z f32[36864] |
//     ot f32[65536] | Wbf ushort[37748736]

#define Ii 64
#define Jj 1152
#define Kk 32
#define Bb 32
#define NJB2 72     // J / 16

typedef short  bf16x8 __attribute__((ext_vector_type(8)));
typedef float  f32x16 __attribute__((ext_vector_type(16)));
typedef float  f32x4  __attribute__((ext_vector_type(4)));

__device__ __forceinline__ void split2(float a, float b, unsigned &hi, unsigned &lo){
  unsigned ua = __float_as_uint(a), ub = __float_as_uint(b);
  unsigned ha = ua & 0xFFFF0000u, hb = ub & 0xFFFF0000u;
  hi = (ha >> 16) | hb;
  float la = a - __uint_as_float(ha);
  float lb = b - __uint_as_float(hb);
  lo = ((__float_as_uint(la) & 0xFFFF0000u) >> 16) | (__float_as_uint(lb) & 0xFFFF0000u);
}

__device__ __forceinline__ void split8(const float* v, bf16x8 &hi, bf16x8 &lo){
  union U { bf16x8 v; unsigned u[4]; } H, L;
#pragma unroll
  for (int p=0;p<4;p++) split2(v[2*p], v[2*p+1], H.u[p], L.u[p]);
  hi = H.v; lo = L.v;
}

__device__ __forceinline__ ushort f2bf_rne(float f){
  unsigned u = __float_as_uint(f);
  return (ushort)((u + 0x7FFFu + ((u >> 16) & 1u)) >> 16);
}

#define MFMA(A,B,C) __builtin_amdgcn_mfma_f32_32x32x16_bf16(A,B,C,0,0,0)

// ---- s pass: block = (16 j) x (4 i); acc in regs, reduce in epilogue ----
// FIRST=1: read f32 W, emit bf16 W, 3-MFMA split, 2 blocks/CU (HBM-bound).
// FIRST=0: read bf16 W, 2-MFMA, 4 blocks/CU.
template<int FIRST>
__global__ __launch_bounds__(256, FIRST ? 2 : 4)
void k_s(const float* __restrict__ Wp, const ushort* __restrict__ Wbi,
         ushort* __restrict__ Wbo, const float* __restrict__ xp,
         const float* __restrict__ brt, const float* __restrict__ zp,
         ushort* __restrict__ spart)
{
  __shared__ float red[4*1088];
  const int t  = threadIdx.x;
  const int w  = t >> 6, lane = t & 63;
  const int kk = lane & 31;
  const int h  = lane >> 5;
  const int b  = lane & 31;
  const int i0 = blockIdx.y * 4;
  const int j0 = blockIdx.x * 16 + w * 4;   // this wave's 4 j's

  // x fragments: load + split once, reuse across all 4 i
  bf16x8 Bh[4], Bl[4];
  float zi[4];
#pragma unroll
  for (int jj=0;jj<4;jj++){
    const int j = j0 + jj;
    float x8[8];
    *(f32x4*)(x8)   = *(const f32x4*)(xp + (b*Jj + j)*16 + h*8);
    *(f32x4*)(x8+4) = *(const f32x4*)(xp + (b*Jj + j)*16 + h*8 + 4);
    split8(x8, Bh[jj], Bl[jj]);
    if (!FIRST) zi[jj] = 1.0f / zp[j*32 + b];
  }

  f32x16 acc[4];
#pragma unroll
  for (int ii=0;ii<4;ii++) acc[ii] = {};

#pragma unroll
  for (int ii=0; ii<4; ++ii){
    const int i = i0 + ii;
#pragma unroll
    for (int jj=0;jj<4;jj++){
      const size_t eoff = (size_t)(i*Jj + j0+jj)*512 + kk*16 + h*8;
      f32x16 d = {};
      if (FIRST){
        float w8[8];
        *(f32x4*)(w8)   = *(const f32x4*)(Wp + eoff);
        *(f32x4*)(w8+4) = *(const f32x4*)(Wp + eoff + 4);
        bf16x8 Ah, Al;
        split8(w8, Ah, Al);
        *reinterpret_cast<bf16x8*>(Wbo + eoff) = Ah;   // emit bf16 W
        d = MFMA(Ah, Bh[jj], d);
        d = MFMA(Ah, Bl[jj], d);
        d = MFMA(Al, Bh[jj], d);
      } else {
        const bf16x8 Ah = *reinterpret_cast<const bf16x8*>(Wbi + eoff);
        d = MFMA(Ah, Bh[jj], d);
        d = MFMA(Ah, Bl[jj], d);
      }
      float cw;
      if (FIRST) cw = 0.015625f;
      else {
        const float bv = brt[(i*Jj + j0+jj)*32 + b];
        cw = __expf(bv) * zi[jj];
      }
#pragma unroll
      for (int r=0;r<16;r++) acc[ii][r] += cw * d[r];
    }
  }

  // epilogue: cross-wave reduce per i (stride-17 rows: conflict-free)
#pragma unroll
  for (int ii=0; ii<4; ++ii){
    __syncthreads();
#pragma unroll
    for (int r=0;r<16;r++) red[w*1088 + lane*17 + r] = acc[ii][r];
    __syncthreads();
    ushort4 outv;
    {
      float s0=0.f, s1=0.f, s2v=0.f, s3=0.f;
#pragma unroll
      for (int q=0;q<4;q++){
        const int v  = t*4 + q;
        const int lv = v >> 4, r = v & 15;
        float sum = 0.f;
#pragma unroll
        for (int ww=0;ww<4;ww++) sum += red[ww*1088 + lv*17 + r];
        if (q==0) s0=sum; else if (q==1) s1=sum; else if (q==2) s2v=sum; else s3=sum;
      }
      outv.x = f2bf_rne(s0); outv.y = f2bf_rne(s1);
      outv.z = f2bf_rne(s2v); outv.w = f2bf_rne(s3);
    }
    *(ushort4*)&spart[((size_t)blockIdx.x*Ii + (i0+ii))*1024 + t*4] = outv;
  }
}

// ---- reduce 72 bf16 partials + squash; TR=1 -> o_t[i][k][b], else out ----
// ZZ=1: also zero z for the following k_ag.
template<int TR, int ZZ>
__global__ __launch_bounds__(256)
void k_redsq(const ushort* __restrict__ spart, float* __restrict__ outp,
             float* __restrict__ zp)
{
  const int i = blockIdx.x, t = threadIdx.x;
  if (ZZ){
    const int base = blockIdx.x * 576;     // 64 blocks x 576 = 36864
    zp[base + t] = 0.f;
    zp[base + 256 + t] = 0.f;
    if (t < 64) zp[base + 512 + t] = 0.f;
  }
  float a0=0.f, a1=0.f, a2=0.f, a3=0.f;
#pragma unroll 8
  for (int jb=0;jb<NJB2;jb++){
    const ushort4 u = *(const ushort4*)&spart[((size_t)jb*Ii + i)*1024 + t*4];
    a0 += __uint_as_float((unsigned)u.x << 16);
    a1 += __uint_as_float((unsigned)u.y << 16);
    a2 += __uint_as_float((unsigned)u.z << 16);
    a3 += __uint_as_float((unsigned)u.w << 16);
  }

  const int b2 = (t>>2)&31, hh = t>>7, t3 = t&3;
  float ss = a0*a0 + a1*a1 + a2*a2 + a3*a3;
  ss += __shfl_xor(ss,1);
  ss += __shfl_xor(ss,2);
  __shared__ float sp2[2][32];
  if (t3 == 0) sp2[hh][b2] = ss;
  __syncthreads();
  const float s2 = sp2[0][b2] + sp2[1][b2];
  const float scale = s2/(1.f+s2) * rsqrtf(s2 + 1e-7f);
  const float vals[4] = {a0*scale, a1*scale, a2*scale, a3*scale};
#pragma unroll
  for (int q=0;q<4;q++){
    const int kcap = q + 8*t3 + 4*hh;
    if (TR) outp[(i*Kk + kcap)*Bb + b2] = vals[q];
    else    outp[((size_t)b2*Ii + i)*Kk + kcap] = vals[q];
  }
}

// ---- agree pass (bf16 W, IT=4): br_t (+)= o.u_hat; z[j,b] += exp(br_new) -
template<int ADD>
__global__ __launch_bounds__(256, 4)
void k_ag(const ushort* __restrict__ Wb, const float* __restrict__ xp,
          const float* __restrict__ ot, float* __restrict__ brt,
          float* __restrict__ zp)
{
  const int t  = threadIdx.x;
  const int w  = t >> 6, lane = t & 63;
  const int kk = lane & 31;
  const int h  = lane >> 5;
  const int b  = lane & 31;
  const int i0 = blockIdx.y * 4;
  const int j0 = blockIdx.x * 16 + w * 4;

  bf16x8 Bh[4], Bl[4];
#pragma unroll
  for (int jj=0;jj<4;jj++){
    const int j = j0 + jj;
    float x8[8];
    *(f32x4*)(x8)   = *(const f32x4*)(xp + (b*Jj + j)*16 + h*8);
    *(f32x4*)(x8+4) = *(const f32x4*)(xp + (b*Jj + j)*16 + h*8 + 4);
    split8(x8, Bh[jj], Bl[jj]);
  }

  float ez[4] = {0.f, 0.f, 0.f, 0.f};

#pragma unroll
  for (int ii=0; ii<4; ++ii){
    const int i = i0 + ii;
    float ov[16];
#pragma unroll
    for (int r=0;r<16;r++){
      const int kcap = (r & 3) + 8*(r >> 2) + 4*h;
      ov[r] = ot[(i*Kk + kcap)*Bb + b];
    }
#pragma unroll
    for (int jj=0;jj<4;jj++){
      const size_t eoff = (size_t)(i*Jj + j0+jj)*512 + kk*16 + h*8;
      const bf16x8 Ah = *reinterpret_cast<const bf16x8*>(Wb + eoff);
      f32x16 d = {};
      d = MFMA(Ah, Bh[jj], d);
      d = MFMA(Ah, Bl[jj], d);
      float ap = 0.f;
#pragma unroll
      for (int r=0;r<16;r++) ap += ov[r]*d[r];
      ap += __shfl_xor(ap, 32);
      if (h == 0){
        const int idx = (i*Jj + j0+jj)*32 + b;
        const float prev = ADD ? brt[idx] : 0.f;
        const float bn = prev + ap;
        brt[idx] = bn;
        ez[jj] += __expf(bn);
      }
    }
  }
  if (h == 0){
#pragma unroll
    for (int jj=0;jj<4;jj++)
      atomicAdd(&zp[(j0+jj)*32 + b], ez[jj]);
  }
}

extern "C" void kernel_launch(void* const* d_in, const int* in_sizes, int n_in,
                              void* d_out, int out_size, void* d_ws, size_t ws_size,
                              hipStream_t stream)
{
  const float* x  = (const float*)d_in[0];   // [B,J,M]
  const float* Wp = (const float*)d_in[1];   // [I,J,K,M]
  float* out = (float*)d_out;                // [B,I,K]
  float* ws  = (float*)d_ws;
  ushort* spart = (ushort*)ws;               // 4718592 ushorts (9.4MB)
  float* br    = ws + 2359296;               // 2359296 floats
  float* z     = ws + 4718592;               // 36864 floats
  float* ot    = ws + 4755456;               // 65536 floats
  ushort* Wbf  = (ushort*)(ws + 4820992);    // 37748736 ushorts (75.5MB)

  dim3 gs(NJB2, 16), bs(256);

  // iter 0 (c uniform 1/64); k_s<1> also emits bf16 W
  k_s<1><<<gs, bs, 0, stream>>>(Wp, nullptr, Wbf, x, nullptr, nullptr, spart);
  k_redsq<1,1><<<dim3(64), bs, 0, stream>>>(spart, ot, z);
  k_ag<0><<<gs, bs, 0, stream>>>(Wbf, x, ot, br, z);

  // iter 1
  k_s<0><<<gs, bs, 0, stream>>>(nullptr, Wbf, nullptr, x, br, z, spart);
  k_redsq<1,1><<<dim3(64), bs, 0, stream>>>(spart, ot, z);
  k_ag<1><<<gs, bs, 0, stream>>>(Wbf, x, ot, br, z);

  // iter 2
  k_s<0><<<gs, bs, 0, stream>>>(nullptr, Wbf, nullptr, x, br, z, spart);
  k_redsq<0,0><<<dim3(64), bs, 0, stream>>>(spart, out, nullptr);
}

// Round 12
// 133.873 us; speedup vs baseline: 4.3742x; 1.1421x over previous
//
#include <hip/hip_runtime.h>

// Capsule routing B=32 I=64 J=1152 K=32 M=16, routings=3, via MFMA.
// u_hat[k,b] per (i,j) = one v_mfma_f32_32x32x16_bf16.
// PROVEN-BEST config (= round 7, 136.3us) + ZZ-fused z-zeroing (round 9
// proved neutral at (256,2)):
//  - Sweep 1 (k_s<1>) streams f32 W (3-MFMA split accuracy) AND emits bf16 W.
//  - Sweeps 2-5 read bf16 W (2 MFMA; x hi/lo split). IT=4, (256,2) EVERYWHERE
//    (R8/R9/R11: IT=2/IT=8/launch_bounds(256,4) all regress; sweeps are at
//    their byte floor ~94MB/15us at (256,2)).
//  - spart stored bf16; k_redsq reduces 72 partials + squash (+ zeroes z).
//  - softmax w/o max-subtraction (|b|<~25 f32-safe): z via atomicAdd in k_ag;
//    k_s uses c = exp(b)/z.
//  - NO device-scope fences in-kernel (R10: threadfence storm = 4x slower).
// ws: spart ushort[4718592] | br f32[2359296] | z f32[36864] |
//     ot f32[65536] | Wbf ushort[37748736]

#define Ii 64
#define Jj 1152
#define Kk 32
#define Bb 32
#define NJB2 72     // J / 16

typedef short  bf16x8 __attribute__((ext_vector_type(8)));
typedef float  f32x16 __attribute__((ext_vector_type(16)));
typedef float  f32x4  __attribute__((ext_vector_type(4)));

__device__ __forceinline__ void split2(float a, float b, unsigned &hi, unsigned &lo){
  unsigned ua = __float_as_uint(a), ub = __float_as_uint(b);
  unsigned ha = ua & 0xFFFF0000u, hb = ub & 0xFFFF0000u;
  hi = (ha >> 16) | hb;
  float la = a - __uint_as_float(ha);
  float lb = b - __uint_as_float(hb);
  lo = ((__float_as_uint(la) & 0xFFFF0000u) >> 16) | (__float_as_uint(lb) & 0xFFFF0000u);
}

__device__ __forceinline__ void split8(const float* v, bf16x8 &hi, bf16x8 &lo){
  union U { bf16x8 v; unsigned u[4]; } H, L;
#pragma unroll
  for (int p=0;p<4;p++) split2(v[2*p], v[2*p+1], H.u[p], L.u[p]);
  hi = H.v; lo = L.v;
}

__device__ __forceinline__ ushort f2bf_rne(float f){
  unsigned u = __float_as_uint(f);
  return (ushort)((u + 0x7FFFu + ((u >> 16) & 1u)) >> 16);
}

#define MFMA(A,B,C) __builtin_amdgcn_mfma_f32_32x32x16_bf16(A,B,C,0,0,0)

// ---- s pass: block = (16 j) x (4 i); acc in regs, reduce in epilogue -----
// FIRST=1: read f32 W, emit bf16 W, 3-MFMA split. FIRST=0: read bf16 W, 2-MFMA.
template<int FIRST>
__global__ __launch_bounds__(256, 2)
void k_s(const float* __restrict__ Wp, const ushort* __restrict__ Wbi,
         ushort* __restrict__ Wbo, const float* __restrict__ xp,
         const float* __restrict__ brt, const float* __restrict__ zp,
         ushort* __restrict__ spart)
{
  __shared__ float red[4*1088];
  const int t  = threadIdx.x;
  const int w  = t >> 6, lane = t & 63;
  const int kk = lane & 31;
  const int h  = lane >> 5;
  const int b  = lane & 31;
  const int i0 = blockIdx.y * 4;
  const int j0 = blockIdx.x * 16 + w * 4;   // this wave's 4 j's

  // x fragments: load + split once, reuse across all 4 i
  bf16x8 Bh[4], Bl[4];
  float zi[4];
#pragma unroll
  for (int jj=0;jj<4;jj++){
    const int j = j0 + jj;
    float x8[8];
    *(f32x4*)(x8)   = *(const f32x4*)(xp + (b*Jj + j)*16 + h*8);
    *(f32x4*)(x8+4) = *(const f32x4*)(xp + (b*Jj + j)*16 + h*8 + 4);
    split8(x8, Bh[jj], Bl[jj]);
    if (!FIRST) zi[jj] = 1.0f / zp[j*32 + b];
  }

  f32x16 acc[4];
#pragma unroll
  for (int ii=0;ii<4;ii++) acc[ii] = {};

#pragma unroll
  for (int ii=0; ii<4; ++ii){
    const int i = i0 + ii;
#pragma unroll
    for (int jj=0;jj<4;jj++){
      const size_t eoff = (size_t)(i*Jj + j0+jj)*512 + kk*16 + h*8;
      f32x16 d = {};
      if (FIRST){
        float w8[8];
        *(f32x4*)(w8)   = *(const f32x4*)(Wp + eoff);
        *(f32x4*)(w8+4) = *(const f32x4*)(Wp + eoff + 4);
        bf16x8 Ah, Al;
        split8(w8, Ah, Al);
        *reinterpret_cast<bf16x8*>(Wbo + eoff) = Ah;   // emit bf16 W
        d = MFMA(Ah, Bh[jj], d);
        d = MFMA(Ah, Bl[jj], d);
        d = MFMA(Al, Bh[jj], d);
      } else {
        const bf16x8 Ah = *reinterpret_cast<const bf16x8*>(Wbi + eoff);
        d = MFMA(Ah, Bh[jj], d);
        d = MFMA(Ah, Bl[jj], d);
      }
      float cw;
      if (FIRST) cw = 0.015625f;
      else {
        const float bv = brt[(i*Jj + j0+jj)*32 + b];
        cw = __expf(bv) * zi[jj];
      }
#pragma unroll
      for (int r=0;r<16;r++) acc[ii][r] += cw * d[r];
    }
  }

  // epilogue: cross-wave reduce per i (stride-17 rows: conflict-free)
#pragma unroll
  for (int ii=0; ii<4; ++ii){
    __syncthreads();
#pragma unroll
    for (int r=0;r<16;r++) red[w*1088 + lane*17 + r] = acc[ii][r];
    __syncthreads();
    ushort4 outv;
    {
      float s0=0.f, s1=0.f, s2v=0.f, s3=0.f;
#pragma unroll
      for (int q=0;q<4;q++){
        const int v  = t*4 + q;
        const int lv = v >> 4, r = v & 15;
        float sum = 0.f;
#pragma unroll
        for (int ww=0;ww<4;ww++) sum += red[ww*1088 + lv*17 + r];
        if (q==0) s0=sum; else if (q==1) s1=sum; else if (q==2) s2v=sum; else s3=sum;
      }
      outv.x = f2bf_rne(s0); outv.y = f2bf_rne(s1);
      outv.z = f2bf_rne(s2v); outv.w = f2bf_rne(s3);
    }
    *(ushort4*)&spart[((size_t)blockIdx.x*Ii + (i0+ii))*1024 + t*4] = outv;
  }
}

// ---- reduce 72 bf16 partials + squash; TR=1 -> o_t[i][k][b], else out ----
// ZZ=1: also zero z for the following k_ag.
template<int TR, int ZZ>
__global__ __launch_bounds__(256)
void k_redsq(const ushort* __restrict__ spart, float* __restrict__ outp,
             float* __restrict__ zp)
{
  const int i = blockIdx.x, t = threadIdx.x;
  if (ZZ){
    const int base = blockIdx.x * 576;     // 64 blocks x 576 = 36864
    zp[base + t] = 0.f;
    zp[base + 256 + t] = 0.f;
    if (t < 64) zp[base + 512 + t] = 0.f;
  }
  float a0=0.f, a1=0.f, a2=0.f, a3=0.f;
#pragma unroll 8
  for (int jb=0;jb<NJB2;jb++){
    const ushort4 u = *(const ushort4*)&spart[((size_t)jb*Ii + i)*1024 + t*4];
    a0 += __uint_as_float((unsigned)u.x << 16);
    a1 += __uint_as_float((unsigned)u.y << 16);
    a2 += __uint_as_float((unsigned)u.z << 16);
    a3 += __uint_as_float((unsigned)u.w << 16);
  }

  const int b2 = (t>>2)&31, hh = t>>7, t3 = t&3;
  float ss = a0*a0 + a1*a1 + a2*a2 + a3*a3;
  ss += __shfl_xor(ss,1);
  ss += __shfl_xor(ss,2);
  __shared__ float sp2[2][32];
  if (t3 == 0) sp2[hh][b2] = ss;
  __syncthreads();
  const float s2 = sp2[0][b2] + sp2[1][b2];
  const float scale = s2/(1.f+s2) * rsqrtf(s2 + 1e-7f);
  const float vals[4] = {a0*scale, a1*scale, a2*scale, a3*scale};
#pragma unroll
  for (int q=0;q<4;q++){
    const int kcap = q + 8*t3 + 4*hh;
    if (TR) outp[(i*Kk + kcap)*Bb + b2] = vals[q];
    else    outp[((size_t)b2*Ii + i)*Kk + kcap] = vals[q];
  }
}

// ---- agree pass (bf16 W, IT=4): br_t (+)= o.u_hat; z[j,b] += exp(br_new) -
template<int ADD>
__global__ __launch_bounds__(256, 2)
void k_ag(const ushort* __restrict__ Wb, const float* __restrict__ xp,
          const float* __restrict__ ot, float* __restrict__ brt,
          float* __restrict__ zp)
{
  const int t  = threadIdx.x;
  const int w  = t >> 6, lane = t & 63;
  const int kk = lane & 31;
  const int h  = lane >> 5;
  const int b  = lane & 31;
  const int i0 = blockIdx.y * 4;
  const int j0 = blockIdx.x * 16 + w * 4;

  bf16x8 Bh[4], Bl[4];
#pragma unroll
  for (int jj=0;jj<4;jj++){
    const int j = j0 + jj;
    float x8[8];
    *(f32x4*)(x8)   = *(const f32x4*)(xp + (b*Jj + j)*16 + h*8);
    *(f32x4*)(x8+4) = *(const f32x4*)(xp + (b*Jj + j)*16 + h*8 + 4);
    split8(x8, Bh[jj], Bl[jj]);
  }

  float ez[4] = {0.f, 0.f, 0.f, 0.f};

#pragma unroll
  for (int ii=0; ii<4; ++ii){
    const int i = i0 + ii;
    float ov[16];
#pragma unroll
    for (int r=0;r<16;r++){
      const int kcap = (r & 3) + 8*(r >> 2) + 4*h;
      ov[r] = ot[(i*Kk + kcap)*Bb + b];
    }
#pragma unroll
    for (int jj=0;jj<4;jj++){
      const size_t eoff = (size_t)(i*Jj + j0+jj)*512 + kk*16 + h*8;
      const bf16x8 Ah = *reinterpret_cast<const bf16x8*>(Wb + eoff);
      f32x16 d = {};
      d = MFMA(Ah, Bh[jj], d);
      d = MFMA(Ah, Bl[jj], d);
      float ap = 0.f;
#pragma unroll
      for (int r=0;r<16;r++) ap += ov[r]*d[r];
      ap += __shfl_xor(ap, 32);
      if (h == 0){
        const int idx = (i*Jj + j0+jj)*32 + b;
        const float prev = ADD ? brt[idx] : 0.f;
        const float bn = prev + ap;
        brt[idx] = bn;
        ez[jj] += __expf(bn);
      }
    }
  }
  if (h == 0){
#pragma unroll
    for (int jj=0;jj<4;jj++)
      atomicAdd(&zp[(j0+jj)*32 + b], ez[jj]);
  }
}

extern "C" void kernel_launch(void* const* d_in, const int* in_sizes, int n_in,
                              void* d_out, int out_size, void* d_ws, size_t ws_size,
                              hipStream_t stream)
{
  const float* x  = (const float*)d_in[0];   // [B,J,M]
  const float* Wp = (const float*)d_in[1];   // [I,J,K,M]
  float* out = (float*)d_out;                // [B,I,K]
  float* ws  = (float*)d_ws;
  ushort* spart = (ushort*)ws;               // 4718592 ushorts (9.4MB)
  float* br    = ws + 2359296;               // 2359296 floats
  float* z     = ws + 4718592;               // 36864 floats
  float* ot    = ws + 4755456;               // 65536 floats
  ushort* Wbf  = (ushort*)(ws + 4820992);    // 37748736 ushorts (75.5MB)

  dim3 gs(NJB2, 16), bs(256);

  // iter 0 (c uniform 1/64); k_s<1> also emits bf16 W
  k_s<1><<<gs, bs, 0, stream>>>(Wp, nullptr, Wbf, x, nullptr, nullptr, spart);
  k_redsq<1,1><<<dim3(64), bs, 0, stream>>>(spart, ot, z);
  k_ag<0><<<gs, bs, 0, stream>>>(Wbf, x, ot, br, z);

  // iter 1
  k_s<0><<<gs, bs, 0, stream>>>(nullptr, Wbf, nullptr, x, br, z, spart);
  k_redsq<1,1><<<dim3(64), bs, 0, stream>>>(spart, ot, z);
  k_ag<1><<<gs, bs, 0, stream>>>(Wbf, x, ot, br, z);

  // iter 2
  k_s<0><<<gs, bs, 0, stream>>>(nullptr, Wbf, nullptr, x, br, z, spart);
  k_redsq<0,0><<<dim3(64), bs, 0, stream>>>(spart, out, nullptr);
}